// Round 4
// baseline (450.551 us; speedup 1.0000x reference)
//
#include <hip/hip_runtime.h>

// LIF scan over trailing time axis T=16.
// X: [4194304 pixels][16 timesteps] fp32, T contiguous.
//
// Structure: coalesced float4 global I/O + LDS transpose (257-pad, conflict
// free) + register scan. 4 tiles per block with the next tile's global loads
// issued during the current tile's compute phase; nontemporal stores via
// native ext_vector_type (HIP float4 class is rejected by the NT builtin).
// Single LDS buffer (16.4 KB) keeps 8 blocks/CU resident.

#define LIF_DECAY  0.5f
#define LIF_THRESH 1.0f
#define TILES_PER_BLOCK 4

typedef float nfloat4 __attribute__((ext_vector_type(4)));  // native vec for NT ops

#define LIF_STEP(v)                                        \
    {                                                      \
        m = m * LIF_DECAY + (v);                           \
        float sp = (m >= LIF_THRESH) ? 1.0f : 0.0f;        \
        (v) = sp;                                          \
        m = (sp != 0.0f) ? 0.0f : m;                       \
    }

__global__ __launch_bounds__(256) void lif_kernel(const nfloat4* __restrict__ X4,
                                                  nfloat4* __restrict__ O4) {
    __shared__ nfloat4 lds[4 * 257];

    const int tid = threadIdx.x;
    const int q   = tid & 3;      // quarter index for coalesced<->transposed map
    const int plc = tid >> 2;     // pixel_local base for coalesced phases

    size_t base = (size_t)blockIdx.x * (1024 * TILES_PER_BLOCK);

    // Preload tile 0.
    nfloat4 v0 = X4[base + (size_t)(0 * 256 + tid)];
    nfloat4 v1 = X4[base + (size_t)(1 * 256 + tid)];
    nfloat4 v2 = X4[base + (size_t)(2 * 256 + tid)];
    nfloat4 v3 = X4[base + (size_t)(3 * 256 + tid)];

#pragma unroll
    for (int t = 0; t < TILES_PER_BLOCK; ++t) {
        const size_t tbase = base + (size_t)t * 1024;

        if (t > 0) __syncthreads();   // prior tile's phase-4 LDS reads done

        // ---- Phase 1: registers -> LDS (transposed) ----
        lds[q * 257 + (0 * 64 + plc)] = v0;
        lds[q * 257 + (1 * 64 + plc)] = v1;
        lds[q * 257 + (2 * 64 + plc)] = v2;
        lds[q * 257 + (3 * 64 + plc)] = v3;
        __syncthreads();

        // ---- Phase 2: pixel-private read ----
        nfloat4 f0 = lds[0 * 257 + tid];
        nfloat4 f1 = lds[1 * 257 + tid];
        nfloat4 f2 = lds[2 * 257 + tid];
        nfloat4 f3 = lds[3 * 257 + tid];

        // ---- Prefetch next tile while the scan runs ----
        if (t + 1 < TILES_PER_BLOCK) {
            const size_t nbase = tbase + 1024;
            v0 = X4[nbase + (size_t)(0 * 256 + tid)];
            v1 = X4[nbase + (size_t)(1 * 256 + tid)];
            v2 = X4[nbase + (size_t)(2 * 256 + tid)];
            v3 = X4[nbase + (size_t)(3 * 256 + tid)];
        }

        // ---- Phase 3: register scan ----
        float m = 0.0f;
        LIF_STEP(f0.x) LIF_STEP(f0.y) LIF_STEP(f0.z) LIF_STEP(f0.w)
        LIF_STEP(f1.x) LIF_STEP(f1.y) LIF_STEP(f1.z) LIF_STEP(f1.w)
        LIF_STEP(f2.x) LIF_STEP(f2.y) LIF_STEP(f2.z) LIF_STEP(f2.w)
        LIF_STEP(f3.x) LIF_STEP(f3.y) LIF_STEP(f3.z) LIF_STEP(f3.w)

        __syncthreads();   // phase-2 reads done everywhere before LDS reuse

        // ---- Phase 4: spikes -> LDS, coalesced NT store ----
        lds[0 * 257 + tid] = f0;
        lds[1 * 257 + tid] = f1;
        lds[2 * 257 + tid] = f2;
        lds[3 * 257 + tid] = f3;
        __syncthreads();

#pragma unroll
        for (int k = 0; k < 4; ++k) {
            nfloat4 s = lds[q * 257 + (k * 64 + plc)];
            __builtin_nontemporal_store(s, &O4[tbase + (size_t)(k * 256 + tid)]);
        }
    }
}

extern "C" void kernel_launch(void* const* d_in, const int* in_sizes, int n_in,
                              void* d_out, int out_size, void* d_ws, size_t ws_size,
                              hipStream_t stream) {
    (void)n_in; (void)d_ws; (void)ws_size; (void)out_size;
    const nfloat4* X4 = (const nfloat4*)d_in[0];
    nfloat4* O4 = (nfloat4*)d_out;

    int n_f4 = in_sizes[0] / 4;                       // 16,777,216
    int grid = n_f4 / (1024 * TILES_PER_BLOCK);       // 4096
    lif_kernel<<<grid, 256, 0, stream>>>(X4, O4);
}

// Round 5
// 440.626 us; speedup vs baseline: 1.0225x; 1.0225x over previous
//
#include <hip/hip_runtime.h>

// LIF scan over trailing time axis T=16.
// X: [4194304 pixels][16 timesteps] fp32, T contiguous.
//
// R4 lesson: barrier-aligned phases (3x __syncthreads per tile + vmcnt
// drains) left the kernel latency-bound at 2.45 TB/s with VALUBusy=5%.
// R5: wave-autonomous transpose — each wave owns 64 pixels (= exactly its
// 4 coalesced float4 loads) and a PRIVATE LDS region, so the LDS
// round-trip is wave-synchronous (lgkmcnt only, NO s_barrier anywhere).
// Every wave is independent; ~32 waves/CU hide HBM latency.
//
// LDS map (per wave, float4 units, row pad 65): addr = chunk*65 + pixel.
// Both directions distribute 8 lanes per bank-quad = b128 structural
// minimum -> conflict-free.

#define LIF_DECAY  0.5f
#define LIF_THRESH 1.0f
#define PAD 65

typedef float nfloat4 __attribute__((ext_vector_type(4)));

#define LIF_STEP(v)                                        \
    {                                                      \
        m = m * LIF_DECAY + (v);                           \
        float sp = (m >= LIF_THRESH) ? 1.0f : 0.0f;        \
        (v) = sp;                                          \
        m = (sp != 0.0f) ? 0.0f : m;                       \
    }

__global__ __launch_bounds__(256) void lif_kernel(const nfloat4* __restrict__ X4,
                                                  nfloat4* __restrict__ O4) {
    __shared__ nfloat4 lds[4][4 * PAD];   // one private region per wave

    const int tid  = threadIdx.x;
    const int lane = tid & 63;
    const int wid  = tid >> 6;

    // This wave owns 64 pixels = 256 consecutive float4.
    const size_t wbase = ((size_t)blockIdx.x * 4 + wid) * 256;
    nfloat4* __restrict__ L = &lds[wid][0];

    // ---- Coalesced loads: 4x 1KiB per wave ----
    nfloat4 v0 = X4[wbase + (size_t)(0 * 64 + lane)];
    nfloat4 v1 = X4[wbase + (size_t)(1 * 64 + lane)];
    nfloat4 v2 = X4[wbase + (size_t)(2 * 64 + lane)];
    nfloat4 v3 = X4[wbase + (size_t)(3 * 64 + lane)];

    // ---- Transpose in: float4 m=k*64+lane -> pixel p=m>>2, chunk q=m&3 ----
    const int q  = lane & 3;
    const int pl = lane >> 2;
    L[q * PAD + (0 * 16 + pl)] = v0;
    L[q * PAD + (1 * 16 + pl)] = v1;
    L[q * PAD + (2 * 16 + pl)] = v2;
    L[q * PAD + (3 * 16 + pl)] = v3;

    // ---- Pixel-private read: lane = pixel ----
    nfloat4 f0 = L[0 * PAD + lane];
    nfloat4 f1 = L[1 * PAD + lane];
    nfloat4 f2 = L[2 * PAD + lane];
    nfloat4 f3 = L[3 * PAD + lane];

    // ---- Register scan over 16 timesteps ----
    float m = 0.0f;
    LIF_STEP(f0.x) LIF_STEP(f0.y) LIF_STEP(f0.z) LIF_STEP(f0.w)
    LIF_STEP(f1.x) LIF_STEP(f1.y) LIF_STEP(f1.z) LIF_STEP(f1.w)
    LIF_STEP(f2.x) LIF_STEP(f2.y) LIF_STEP(f2.z) LIF_STEP(f2.w)
    LIF_STEP(f3.x) LIF_STEP(f3.y) LIF_STEP(f3.z) LIF_STEP(f3.w)

    // ---- Transpose out ----
    L[0 * PAD + lane] = f0;
    L[1 * PAD + lane] = f1;
    L[2 * PAD + lane] = f2;
    L[3 * PAD + lane] = f3;

    // ---- Coalesced NT stores ----
#pragma unroll
    for (int k = 0; k < 4; ++k) {
        nfloat4 s = L[q * PAD + (k * 16 + pl)];
        __builtin_nontemporal_store(s, &O4[wbase + (size_t)(k * 64 + lane)]);
    }
}

extern "C" void kernel_launch(void* const* d_in, const int* in_sizes, int n_in,
                              void* d_out, int out_size, void* d_ws, size_t ws_size,
                              hipStream_t stream) {
    (void)n_in; (void)d_ws; (void)ws_size; (void)out_size;
    const nfloat4* X4 = (const nfloat4*)d_in[0];
    nfloat4* O4 = (nfloat4*)d_out;

    int n_f4 = in_sizes[0] / 4;          // 16,777,216
    int grid = n_f4 / 1024;              // 16384 blocks x 4 waves x 256 float4
    lif_kernel<<<grid, 256, 0, stream>>>(X4, O4);
}